// Round 11
// baseline (229.643 us; speedup 1.0000x reference)
//
#include <hip/hip_runtime.h>
#include <cstdint>

#define B 64
#define L 512
#define EMB 400
#define KPAD 448
#define H 256
#define NL 3
#define NE 512
#define MAXA 32
#define M_TOT (B * L)

typedef unsigned char u8;
typedef unsigned short u16;
typedef unsigned long long ull;
typedef float f32x4 __attribute__((ext_vector_type(4)));
typedef ull u64x2 __attribute__((ext_vector_type(2)));

// within-64 k permutation so one ds_read_b128 (16 fp8) feeds two K=32 MFMAs:
// byte p holds k per: lo 8B = k (c*8..c*8+7), hi 8B = 32+c*8.. for chunk c=kg
__device__ __forceinline__ int perm64(int k) {
  return (k & ~63) | (((k >> 3) & 3) << 4) | (((k >> 5) & 1) << 3) | (k & 7);
}

__device__ __forceinline__ u8 f2fp8(float f) {
  unsigned u = __builtin_bit_cast(unsigned, f);
  const unsigned s = (u >> 31) << 7;
  unsigned au = u & 0x7fffffffu;
  if (au >= 0x43e00000u) return (u8)(s | 0x7e);          // clamp to 448
  unsigned r = au + 0x7ffffu + ((au >> 20) & 1u);        // RNE in f32 bit domain
  if (r >= 0x3c800000u) {                                 // >= 2^-6: normal
    unsigned e = (r >> 23) - 120u;
    unsigned m = (r >> 20) & 7u;
    return (u8)(s | (e << 3) | m);
  }
  float af = __builtin_bit_cast(float, au);               // subnormal: m = round(|f|*512)
  unsigned m = (unsigned)(af * 512.0f + 0.5f);
  return (u8)(s | m);
}

__device__ __forceinline__ float fp8d(unsigned v) {
  const unsigned e = (v >> 3) & 15, m = v & 7;
  float f;
  if (e == 0) f = (float)m * 0.001953125f;                // m * 2^-9
  else f = __builtin_bit_cast(float, ((e + 120u) << 23) | (m << 20));
  return (v >> 7) ? -f : f;
}

#define GL16(g, l)                                                              \
  __builtin_amdgcn_global_load_lds((const __attribute__((address_space(1))) void*)(g), \
                                   (__attribute__((address_space(3))) void*)(l), 16, 0, 0)

// ---------------------------------------------------------------------------
// fp8 MFMA GEMM, BM=64 x BN=256, BK=64 (bytes == bf16-BK32 geometry), 4 waves.
// Counted-vmcnt double-buffer identical to r8. K args/strides in BYTES(=elems).
// EPI 0: conv; EPI 1: highway dual-B (residual decoded from global A);
// EPI 2: gcn relu((acc+2b)*rden), yv += out.cw, store fp8; EPI 3: yv only.
// ---------------------------------------------------------------------------
template <int EPI>
__global__ __launch_bounds__(256, 2) void gemm64(
    const u8* __restrict__ A, const u8* __restrict__ Bw, const u8* __restrict__ B2w,
    const int K,
    const float* __restrict__ bias1, const float* __restrict__ bias2,
    const float* __restrict__ rden, const float* __restrict__ cw,
    float* __restrict__ yv, u8* __restrict__ Out) {
  constexpr bool HW = (EPI == 1);
  __shared__ u8 Bl0[256 * 64];                 // 16 KB
  __shared__ u8 Bl1[256 * 64];
  __shared__ u8 Al0[64 * 64];                  // 4 KB
  __shared__ u8 Al1[64 * 64];
  __shared__ u8 Cl0[HW ? 256 * 64 : 16];
  __shared__ u8 Cl1[HW ? 256 * 64 : 16];

  const int t = threadIdx.x;
  const int wid = t >> 6, lane = t & 63;
  const int m0 = blockIdx.x * 64;
  const int fr = lane & 15, kg = lane >> 4;
  const int r4 = t >> 2, ksg = t & 3;

  f32x4 acc[4][4] = {};
  f32x4 acc2[4][4] = {};

  auto stage = [&](u8* Ab, u8* Bb, u8* Cb, int kk) {
    const int kc = kk * 64 + ksg * 16;
#pragma unroll
    for (int c = 0; c < 4; ++c)
      GL16(Bw + (size_t)(c * 64 + r4) * K + kc, Bb + (size_t)(c * 256 + wid * 64) * 16);
    if constexpr (HW) {
#pragma unroll
      for (int c = 0; c < 4; ++c)
        GL16(B2w + (size_t)(c * 64 + r4) * K + kc, Cb + (size_t)(c * 256 + wid * 64) * 16);
    }
    GL16(A + (size_t)(m0 + r4) * K + kc, Ab + (size_t)(wid * 64) * 16);
  };
  auto compute = [&](const u8* Ab, const u8* Bb, const u8* Cb) {
    u64x2 af[4], bf[4], cf[4];
#pragma unroll
    for (int i = 0; i < 4; ++i) {
      af[i] = *(const u64x2*)(Ab + ((size_t)(i * 16 + fr) * 4 + kg) * 16);
      bf[i] = *(const u64x2*)(Bb + ((size_t)(wid * 64 + i * 16 + fr) * 4 + kg) * 16);
      if constexpr (HW)
        cf[i] = *(const u64x2*)(Cb + ((size_t)(wid * 64 + i * 16 + fr) * 4 + kg) * 16);
    }
#pragma unroll
    for (int mi = 0; mi < 4; ++mi)
#pragma unroll
      for (int ni = 0; ni < 4; ++ni) {
        acc[mi][ni] = __builtin_amdgcn_mfma_f32_16x16x32_fp8_fp8(af[mi][0], bf[ni][0],
                                                                 acc[mi][ni], 0, 0, 0);
        acc[mi][ni] = __builtin_amdgcn_mfma_f32_16x16x32_fp8_fp8(af[mi][1], bf[ni][1],
                                                                 acc[mi][ni], 0, 0, 0);
        if constexpr (HW) {
          acc2[mi][ni] = __builtin_amdgcn_mfma_f32_16x16x32_fp8_fp8(af[mi][0], cf[ni][0],
                                                                    acc2[mi][ni], 0, 0, 0);
          acc2[mi][ni] = __builtin_amdgcn_mfma_f32_16x16x32_fp8_fp8(af[mi][1], cf[ni][1],
                                                                    acc2[mi][ni], 0, 0, 0);
        }
      }
  };

  const int nk = K >> 6;  // 7 (conv) or 4 (HW/GCN); parity loop is odd-safe
  stage(Al0, Bl0, Cl0, 0);
  for (int kk = 0; kk < nk; ++kk) {
    u8* Ac = (kk & 1) ? Al1 : Al0;
    u8* Bc = (kk & 1) ? Bl1 : Bl0;
    u8* Cc = (kk & 1) ? Cl1 : Cl0;
    u8* An = (kk & 1) ? Al0 : Al1;
    u8* Bn = (kk & 1) ? Bl0 : Bl1;
    u8* Cn = (kk & 1) ? Cl0 : Cl1;
    if (kk + 1 < nk) {
      stage(An, Bn, Cn, kk + 1);
      if constexpr (HW)
        asm volatile("s_waitcnt vmcnt(9)" ::: "memory");
      else
        asm volatile("s_waitcnt vmcnt(5)" ::: "memory");
    } else {
      asm volatile("s_waitcnt vmcnt(0)" ::: "memory");
    }
    __builtin_amdgcn_s_barrier();
    asm volatile("" ::: "memory");
    compute(Ac, Bc, Cc);
    __builtin_amdgcn_s_barrier();
    asm volatile("" ::: "memory");
  }

  // epilogue: C/D mapping col = lane&15, row = (lane>>4)*4 + reg [m89-verified;
  // dtype-independent]. Memory addresses use perm64(col); bias/cw use true col.
  const int r0 = kg * 4;
  const int c0 = wid * 64 + fr;
  if constexpr (EPI == 0) {
#pragma unroll
    for (int ni = 0; ni < 4; ++ni) {
      const int col = c0 + ni * 16;
      const int pc = perm64(col);
#pragma unroll
      for (int mi = 0; mi < 4; ++mi)
#pragma unroll
        for (int rr = 0; rr < 4; ++rr)
          Out[(size_t)(m0 + mi * 16 + r0 + rr) * H + pc] = f2fp8(acc[mi][ni][rr]);
    }
  } else if constexpr (EPI == 1) {
#pragma unroll
    for (int ni = 0; ni < 4; ++ni) {
      const int col = c0 + ni * 16;
      const int pc = perm64(col);
      const float b1 = bias1[col], b2 = bias2[col];
#pragma unroll
      for (int mi = 0; mi < 4; ++mi)
#pragma unroll
        for (int rr = 0; rr < 4; ++rr) {
          const int row = m0 + mi * 16 + r0 + rr;
          const float g = 1.f / (1.f + __expf(-(acc[mi][ni][rr] + b1)));
          const float nn = acc2[mi][ni][rr] + b2;
          const float x = fp8d(A[(size_t)row * H + pc]);  // residual, L2-hot
          Out[(size_t)row * H + pc] = f2fp8(g * nn + (1.f - g) * x);
        }
    }
  } else {
    float ypart[16];
#pragma unroll
    for (int q = 0; q < 16; ++q) ypart[q] = 0.f;
#pragma unroll
    for (int ni = 0; ni < 4; ++ni) {
      const int col = c0 + ni * 16;
      const int pc = perm64(col);
      const float b1 = 2.f * bias1[col];
      const float cwv = cw[col];
#pragma unroll
      for (int mi = 0; mi < 4; ++mi)
#pragma unroll
        for (int rr = 0; rr < 4; ++rr) {
          const int row = m0 + mi * 16 + r0 + rr;
          const float s = (acc[mi][ni][rr] + b1) * rden[row];
          const float rl = s > 0.f ? s : 0.f;
          ypart[mi * 4 + rr] += rl * cwv;
          if constexpr (EPI == 2) Out[(size_t)row * H + pc] = f2fp8(rl);
        }
    }
#pragma unroll
    for (int q = 0; q < 16; ++q) {
      float p = ypart[q];
      p += __shfl_xor(p, 1);
      p += __shfl_xor(p, 2);
      p += __shfl_xor(p, 4);
      p += __shfl_xor(p, 8);
      if (fr == 0) atomicAdd(&yv[m0 + (q >> 2) * 16 + r0 + (q & 3)], p);
    }
  }
}

// T[m,:] = h[m,:] + sum_{s in adj row} h[s,:]  (fp8 in/out, fp32 accum;
// channel permutation commutes with the elementwise sum — no perm needed)
__global__ __launch_bounds__(256) void k_gather(const unsigned* __restrict__ bm,
                                                const u8* __restrict__ h,
                                                u8* __restrict__ T) {
  const int t = threadIdx.x;
  const int tok = blockIdx.x * 8 + (t >> 5);
  const int b = tok >> 9;
  const int c = (t & 31) * 8;
  const uint4* wp4 = (const uint4*)(bm + (size_t)tok * 16);
  const uint4 w0 = wp4[0], w1 = wp4[1], w2 = wp4[2], w3 = wp4[3];
  const unsigned wa[16] = {w0.x, w0.y, w0.z, w0.w, w1.x, w1.y, w1.z, w1.w,
                           w2.x, w2.y, w2.z, w2.w, w3.x, w3.y, w3.z, w3.w};
  float acc[8];
  {
    const ull v = *(const ull*)(h + (size_t)tok * H + c);
#pragma unroll
    for (int i = 0; i < 8; ++i) acc[i] = fp8d((unsigned)(v >> (8 * i)) & 255u);
  }
#pragma unroll
  for (int wi = 0; wi < 16; ++wi) {
    unsigned bits = wa[wi];
    while (bits) {
      const int bit = __ffs(bits) - 1;
      bits &= bits - 1;
      const int s = wi * 32 + bit;
      const ull u = *(const ull*)(h + (size_t)(b * L + s) * H + c);
#pragma unroll
      for (int i = 0; i < 8; ++i) acc[i] += fp8d((unsigned)(u >> (8 * i)) & 255u);
    }
  }
  ull o = 0;
#pragma unroll
  for (int i = 0; i < 8; ++i) o |= (ull)f2fp8(acc[i]) << (8 * i);
  *(ull*)(T + (size_t)tok * H + c) = o;
}

// dedup'd adjacency bitmap
__global__ void k_edges(const int* __restrict__ edges, unsigned* __restrict__ bm) {
  const int t = blockIdx.x * 256 + threadIdx.x;
  const int b = t >> 9, e = t & 511;
  const int u = edges[(size_t)(b * NE + e) * 2 + 0];
  const int v = edges[(size_t)(b * NE + e) * 2 + 1];
  atomicOr(&bm[(size_t)(b * L + u) * 16 + (v >> 5)], 1u << (v & 31));
  atomicOr(&bm[(size_t)(b * L + v) * 16 + (u >> 5)], 1u << (u & 31));
}

// Merged prep: blocks [0,NSEMBT): Semb transpose fp32 -> fp8 [B*L][KPAD]
// (k-permuted); rest: weight cvt (k-permuted) + rden.
#define NSEMBT (B * 56)  // 64 * 7 * 8 (448/64 = 7 e-tiles)
__global__ __launch_bounds__(256) void k_prep(const float* __restrict__ Semb,
                                              const float* __restrict__ W1,
                                              const float* __restrict__ gW,
                                              const float* __restrict__ lW,
                                              const float* __restrict__ gcnW,
                                              const unsigned* __restrict__ bm,
                                              u8* __restrict__ A0,
                                              u8* __restrict__ W1b, u8* __restrict__ HWGb,
                                              u8* __restrict__ HWLb, u8* __restrict__ GCNb,
                                              float* __restrict__ rden) {
  const int t = threadIdx.x;
  if (blockIdx.x < NSEMBT) {
    const int bid = blockIdx.x;
    const int b = bid / 56, rem = bid - b * 56;
    const int e0 = (rem >> 3) * 64, l0 = (rem & 7) * 64;
    __shared__ u8 tile[64][68];
    {
      const int er = t >> 2, ls = (t & 3) * 16;
      if (e0 + er < EMB) {
        const float* src = Semb + ((size_t)b * EMB + e0 + er) * L + l0 + ls;
#pragma unroll
        for (int i = 0; i < 4; ++i) {
          const float4 v = *(const float4*)(src + i * 4);
          tile[er][ls + i * 4 + 0] = f2fp8(v.x);
          tile[er][ls + i * 4 + 1] = f2fp8(v.y);
          tile[er][ls + i * 4 + 2] = f2fp8(v.z);
          tile[er][ls + i * 4 + 3] = f2fp8(v.w);
        }
      } else {
#pragma unroll
        for (int i = 0; i < 16; ++i) tile[er][ls + i] = 0;
      }
    }
    __syncthreads();
    {
      const int lr = t >> 2, es = (t & 3) * 16;
      u8* dst = A0 + (size_t)(b * L + l0 + lr) * KPAD;
      ull r0 = 0, r1 = 0;
#pragma unroll
      for (int i = 0; i < 8; ++i) r0 |= (ull)tile[es + i][lr] << (8 * i);
#pragma unroll
      for (int i = 0; i < 8; ++i) r1 |= (ull)tile[es + 8 + i][lr] << (8 * i);
      *(ull*)(dst + perm64(e0 + es)) = r0;       // 8-aligned runs by construction
      *(ull*)(dst + perm64(e0 + es + 8)) = r1;
    }
    return;
  }
  int i = (blockIdx.x - NSEMBT) * 256 + t;
  if (i < 256 * KPAD) {
    const int o = i / KPAD, k = i - o * KPAD;
    W1b[o * KPAD + perm64(k)] = (k < EMB) ? f2fp8(W1[o * EMB + k]) : (u8)0;
    return;
  }
  i -= 256 * KPAD;
  if (i < 2 * H * H) {
    const int o = i >> 8, k = i & 255;
    HWGb[o * H + perm64(k)] = f2fp8(gW[i]);
    return;
  }
  i -= 2 * H * H;
  if (i < 2 * H * H) {
    const int o = i >> 8, k = i & 255;
    HWLb[o * H + perm64(k)] = f2fp8(lW[i]);
    return;
  }
  i -= 2 * H * H;
  if (i < NL * H * H) {
    const int o = i >> 8, k = i & 255;
    GCNb[o * H + perm64(k)] = f2fp8(gcnW[i]);
    return;
  }
  i -= NL * H * H;
  if (i < M_TOT) {
    const uint4* p = (const uint4*)(bm + (size_t)i * 16);
    int c = 0;
#pragma unroll
    for (int w = 0; w < 4; ++w) {
      const uint4 v = p[w];
      c += __popc(v.x) + __popc(v.y) + __popc(v.z) + __popc(v.w);
    }
    rden[i] = 1.f / (1.f + (float)c);
  }
}

// logits + maskA
__global__ __launch_bounds__(256) void k_logits(const float* __restrict__ yv,
                                                const float* __restrict__ cb,
                                                const float* __restrict__ lw,
                                                const float* __restrict__ lb,
                                                const int* __restrict__ wids,
                                                const int* __restrict__ y1,
                                                const int* __restrict__ y2,
                                                float* __restrict__ out) {
  if (blockIdx.x == B * 2) {
#pragma unroll
    for (int j = 0; j < 8; ++j) {
      const int idx = j * 256 + threadIdx.x;
      const int b = idx >> 5, q = idx & 31;
      out[B * L + idx] = (y1[b] + q <= y2[b]) ? 1.0f : 0.0f;
    }
    return;
  }
  const int b = blockIdx.x >> 1;
  const int m = ((blockIdx.x & 1) << 8) + threadIdx.x;
  __shared__ float ys[512];
  const float cb0 = cb[0];
  ys[threadIdx.x] = fmaxf(yv[(size_t)b * L + threadIdx.x] + cb0, 0.f);
  ys[threadIdx.x + 256] = fmaxf(yv[(size_t)b * L + 256 + threadIdx.x] + cb0, 0.f);
  __syncthreads();
  float acc = lb[m];
  const float4* wr = (const float4*)(lw + (size_t)m * L);
#pragma unroll 4
  for (int l4 = 0; l4 < 128; ++l4) {
    const float4 w4 = wr[l4];
    acc += ys[l4 * 4] * w4.x + ys[l4 * 4 + 1] * w4.y + ys[l4 * 4 + 2] * w4.z +
           ys[l4 * 4 + 3] * w4.w;
  }
  out[(size_t)b * L + m] = (wids[(size_t)b * L + m] != 0) ? acc : -1.0e30f;
}

extern "C" void kernel_launch(void* const* d_in, const int* in_sizes, int n_in,
                              void* d_out, int out_size, void* d_ws, size_t ws_size,
                              hipStream_t stream) {
  (void)in_sizes; (void)n_in; (void)out_size; (void)ws_size;
  const float* Semb      = (const float*)d_in[0];
  const int*   wids      = (const int*)d_in[1];
  const int*   y1        = (const int*)d_in[2];
  const int*   y2        = (const int*)d_in[3];
  const int*   edges     = (const int*)d_in[4];
  const float* W1        = (const float*)d_in[5];
  const float* hw_lin_W  = (const float*)d_in[6];
  const float* hw_lin_b  = (const float*)d_in[7];
  const float* hw_gate_W = (const float*)d_in[8];
  const float* hw_gate_b = (const float*)d_in[9];
  const float* gcn_W     = (const float*)d_in[10];
  const float* gcn_b     = (const float*)d_in[11];
  const float* conv_W    = (const float*)d_in[12];
  const float* conv_b    = (const float*)d_in[13];
  const float* lin_W     = (const float*)d_in[14];
  const float* lin_b     = (const float*)d_in[15];
  float* out = (float*)d_out;

  char* ws = (char*)d_ws;
  const size_t SZA = (size_t)M_TOT * KPAD;       // 14,680,064
  const size_t SZX = (size_t)M_TOT * H;          // 8,388,608
  u8* A0   = (u8*)(ws);
  u8* P0b  = (u8*)(ws + SZA);
  u8* P1b  = (u8*)(ws + SZA + SZX);
  u8* O0   = (u8*)(ws + SZA + 2 * SZX);
  u8* O1   = (u8*)(ws + SZA + 3 * SZX);
  char* wp = ws + SZA + 4 * SZX;
  u8* W1b  = (u8*)(wp);                           // 256*448 = 114,688
  u8* HWGb = (u8*)(wp + 114688);                  // 131,072
  u8* HWLb = (u8*)(wp + 114688 + 131072);         // 131,072
  u8* GCNb = (u8*)(wp + 114688 + 2 * 131072);     // 196,608
  char* sp = wp + 114688 + 2 * 131072 + 196608;
  unsigned* bm   = (unsigned*)(sp);               // 2 MB
  float*    yv   = (float*)(sp + 2097152);        // 128 KB (zeroed w/ bm)
  float*    rden = (float*)(sp + 2097152 + 131072);

  hipMemsetAsync(bm, 0, 2097152 + 131072, stream);
  k_edges<<<dim3(B * NE / 256), 256, 0, stream>>>(edges, bm);

  const int ncvt = 256 * KPAD + 4 * H * H + NL * H * H + M_TOT;
  k_prep<<<dim3(NSEMBT + (ncvt + 255) / 256), 256, 0, stream>>>(
      Semb, W1, hw_gate_W, hw_lin_W, gcn_W, bm, A0, W1b, HWGb, HWLb, GCNb, rden);

  // conv 1x1
  gemm64<0><<<dim3(M_TOT / 64), 256, 0, stream>>>(A0, W1b, nullptr, KPAD, nullptr, nullptr,
                                                  nullptr, nullptr, nullptr, P0b);
  // highway x2 (gate + lin fused; residual decoded from A)
  gemm64<1><<<dim3(M_TOT / 64), 256, 0, stream>>>(P0b, HWGb, HWLb, H, hw_gate_b, hw_lin_b,
                                                  nullptr, nullptr, nullptr, P1b);
  gemm64<1><<<dim3(M_TOT / 64), 256, 0, stream>>>(P1b, HWGb + H * H, HWLb + H * H, H,
                                                  hw_gate_b + H, hw_lin_b + H, nullptr, nullptr,
                                                  nullptr, P0b);
  // GCN layers: high-TLP gather, then GEMM w/ fused yv accumulation
  k_gather<<<dim3(M_TOT / 8), 256, 0, stream>>>(bm, P0b, P1b);
  gemm64<2><<<dim3(M_TOT / 64), 256, 0, stream>>>(P1b, GCNb, nullptr, H, gcn_b, nullptr,
                                                  rden, conv_W, yv, O0);
  k_gather<<<dim3(M_TOT / 8), 256, 0, stream>>>(bm, O0, P0b);
  gemm64<2><<<dim3(M_TOT / 64), 256, 0, stream>>>(P0b, GCNb + H * H, nullptr, H, gcn_b + H,
                                                  nullptr, rden, conv_W + H, yv, O1);
  k_gather<<<dim3(M_TOT / 8), 256, 0, stream>>>(bm, O1, P1b);
  gemm64<3><<<dim3(M_TOT / 64), 256, 0, stream>>>(P1b, GCNb + 2 * H * H, nullptr, H,
                                                  gcn_b + 2 * H, nullptr, rden,
                                                  conv_W + 2 * H, yv, nullptr);

  k_logits<<<dim3(B * 2 + 1), 256, 0, stream>>>(yv, conv_b, lin_W, lin_b, wids, y1, y2, out);
}

// Round 12
// 180.919 us; speedup vs baseline: 1.2693x; 1.2693x over previous
//
#include <hip/hip_runtime.h>
#include <cstdint>

#define B 64
#define L 512
#define EMB 400
#define KPAD 416
#define H 256
#define NL 3
#define NE 512
#define MAXA 32
#define M_TOT (B * L)

typedef unsigned short u16;
typedef float f32x4 __attribute__((ext_vector_type(4)));
typedef short short8 __attribute__((ext_vector_type(8)));
typedef u16 u16x8 __attribute__((ext_vector_type(8)));

__device__ __forceinline__ float b2f(u16 u) {
  unsigned v = ((unsigned)u) << 16;
  return __builtin_bit_cast(float, v);
}
__device__ __forceinline__ u16 f2b(float f) {
  unsigned u = __builtin_bit_cast(unsigned, f);
  unsigned r = (u + 0x7fffu + ((u >> 16) & 1u)) >> 16;
  return (u16)r;
}

#define GL16(g, l)                                                              \
  __builtin_amdgcn_global_load_lds((const __attribute__((address_space(1))) void*)(g), \
                                   (__attribute__((address_space(3))) void*)(l), 16, 0, 0)

// ---------------------------------------------------------------------------
// bf16 MFMA GEMM, BM=64 x BN=256 (full H), BK=32, 256 threads = 4 waves (1x4).
// Counted-vmcnt double-buffer (r8-proven): stage(k+1) -> vmcnt(J) -> barrier
// -> compute(k) -> barrier.
// EPI 0: conv; EPI 1: highway dual-B (residual re-read from global A);
// EPI 2: gcn relu((acc+2b)*rden), yv += out.cw, store; EPI 3: gcn last (yv only)
// ---------------------------------------------------------------------------
template <int EPI>
__global__ __launch_bounds__(256, 2) void gemm64(
    const u16* __restrict__ A, const u16* __restrict__ Bw, const u16* __restrict__ B2w,
    const int K,
    const float* __restrict__ bias1, const float* __restrict__ bias2,
    const float* __restrict__ rden, const float* __restrict__ cw,
    float* __restrict__ yv, u16* __restrict__ Out) {
  constexpr bool HW = (EPI == 1);
  __shared__ u16 Bl0[256 * 32];
  __shared__ u16 Bl1[256 * 32];
  __shared__ u16 Al0[64 * 32];
  __shared__ u16 Al1[64 * 32];
  __shared__ u16 Cl0[HW ? 256 * 32 : 8];
  __shared__ u16 Cl1[HW ? 256 * 32 : 8];

  const int t = threadIdx.x;
  const int wid = t >> 6, lane = t & 63;
  const int m0 = blockIdx.x * 64;
  const int fr = lane & 15, kg = lane >> 4;
  const int r4 = t >> 2, ksg = t & 3;

  f32x4 acc[4][4] = {};
  f32x4 acc2[4][4] = {};

  auto stage = [&](u16* Ab, u16* Bb, u16* Cb, int kk) {
    const int kc = kk * 32 + ksg * 8;
#pragma unroll
    for (int c = 0; c < 4; ++c)
      GL16(Bw + (size_t)(c * 64 + r4) * K + kc, Bb + (size_t)(c * 256 + wid * 64) * 8);
    if constexpr (HW) {
#pragma unroll
      for (int c = 0; c < 4; ++c)
        GL16(B2w + (size_t)(c * 64 + r4) * K + kc, Cb + (size_t)(c * 256 + wid * 64) * 8);
    }
    GL16(A + (size_t)(m0 + r4) * K + kc, Ab + (size_t)(wid * 64) * 8);
  };
  auto compute = [&](const u16* Ab, const u16* Bb, const u16* Cb) {
    short8 af[4], bf[4], cf[4];
#pragma unroll
    for (int i = 0; i < 4; ++i) {
      af[i] = *(const short8*)(Ab + ((size_t)(i * 16 + fr) * 4 + kg) * 8);
      bf[i] = *(const short8*)(Bb + ((size_t)(wid * 64 + i * 16 + fr) * 4 + kg) * 8);
      if constexpr (HW)
        cf[i] = *(const short8*)(Cb + ((size_t)(wid * 64 + i * 16 + fr) * 4 + kg) * 8);
    }
#pragma unroll
    for (int mi = 0; mi < 4; ++mi)
#pragma unroll
      for (int ni = 0; ni < 4; ++ni) {
        acc[mi][ni] = __builtin_amdgcn_mfma_f32_16x16x32_bf16(af[mi], bf[ni], acc[mi][ni], 0, 0, 0);
        if constexpr (HW)
          acc2[mi][ni] =
              __builtin_amdgcn_mfma_f32_16x16x32_bf16(af[mi], cf[ni], acc2[mi][ni], 0, 0, 0);
      }
  };

  const int nk = K >> 5;  // 13 (conv) or 8 (HW/GCN); loop is odd-nk-safe
  stage(Al0, Bl0, Cl0, 0);
  for (int kk = 0; kk < nk; ++kk) {
    u16* Ac = (kk & 1) ? Al1 : Al0;
    u16* Bc = (kk & 1) ? Bl1 : Bl0;
    u16* Cc = (kk & 1) ? Cl1 : Cl0;
    u16* An = (kk & 1) ? Al0 : Al1;
    u16* Bn = (kk & 1) ? Bl0 : Bl1;
    u16* Cn = (kk & 1) ? Cl0 : Cl1;
    if (kk + 1 < nk) {
      stage(An, Bn, Cn, kk + 1);
      if constexpr (HW)
        asm volatile("s_waitcnt vmcnt(9)" ::: "memory");
      else
        asm volatile("s_waitcnt vmcnt(5)" ::: "memory");
    } else {
      asm volatile("s_waitcnt vmcnt(0)" ::: "memory");
    }
    __builtin_amdgcn_s_barrier();
    asm volatile("" ::: "memory");
    compute(Ac, Bc, Cc);
    __builtin_amdgcn_s_barrier();
    asm volatile("" ::: "memory");
  }

  // epilogue: C/D mapping col = lane&15, row = (lane>>4)*4 + reg [m89-verified]
  const int r0 = kg * 4;
  const int c0 = wid * 64 + fr;
  if constexpr (EPI == 0) {
#pragma unroll
    for (int ni = 0; ni < 4; ++ni) {
      const int col = c0 + ni * 16;
#pragma unroll
      for (int mi = 0; mi < 4; ++mi)
#pragma unroll
        for (int rr = 0; rr < 4; ++rr)
          Out[(size_t)(m0 + mi * 16 + r0 + rr) * H + col] = f2b(acc[mi][ni][rr]);
    }
  } else if constexpr (EPI == 1) {
#pragma unroll
    for (int ni = 0; ni < 4; ++ni) {
      const int col = c0 + ni * 16;
      const float b1 = bias1[col], b2 = bias2[col];
#pragma unroll
      for (int mi = 0; mi < 4; ++mi)
#pragma unroll
        for (int rr = 0; rr < 4; ++rr) {
          const int row = m0 + mi * 16 + r0 + rr;
          const float g = 1.f / (1.f + __expf(-(acc[mi][ni][rr] + b1)));
          const float nn = acc2[mi][ni][rr] + b2;
          const float x = b2f(A[(size_t)row * K + col]);  // residual, L2-hot
          Out[(size_t)row * H + col] = f2b(g * nn + (1.f - g) * x);
        }
    }
  } else {
    float ypart[16];
#pragma unroll
    for (int q = 0; q < 16; ++q) ypart[q] = 0.f;
#pragma unroll
    for (int ni = 0; ni < 4; ++ni) {
      const int col = c0 + ni * 16;
      const float b1 = 2.f * bias1[col];
      const float cwv = cw[col];
#pragma unroll
      for (int mi = 0; mi < 4; ++mi)
#pragma unroll
        for (int rr = 0; rr < 4; ++rr) {
          const int row = m0 + mi * 16 + r0 + rr;
          const float s = (acc[mi][ni][rr] + b1) * rden[row];
          const float rl = s > 0.f ? s : 0.f;
          ypart[mi * 4 + rr] += rl * cwv;
          if constexpr (EPI == 2) Out[(size_t)row * H + col] = f2b(rl);
        }
    }
#pragma unroll
    for (int q = 0; q < 16; ++q) {
      float p = ypart[q];
      p += __shfl_xor(p, 1);
      p += __shfl_xor(p, 2);
      p += __shfl_xor(p, 4);
      p += __shfl_xor(p, 8);
      if (fr == 0) atomicAdd(&yv[m0 + (q >> 2) * 16 + r0 + (q & 3)], p);
    }
  }
}

// T[m,:] = h[m,:] + sum_{s in adj row} h[s,:]
// 8 tokens/block, 32 lanes/token, u16x8 loads; high TLP hides walk latency.
__global__ __launch_bounds__(256) void k_gather(const unsigned* __restrict__ bm,
                                                const u16* __restrict__ h,
                                                u16* __restrict__ T) {
  const int t = threadIdx.x;
  const int tok = blockIdx.x * 8 + (t >> 5);
  const int b = tok >> 9;
  const int c = (t & 31) * 8;
  const uint4* wp4 = (const uint4*)(bm + (size_t)tok * 16);
  const uint4 w0 = wp4[0], w1 = wp4[1], w2 = wp4[2], w3 = wp4[3];
  const unsigned wa[16] = {w0.x, w0.y, w0.z, w0.w, w1.x, w1.y, w1.z, w1.w,
                           w2.x, w2.y, w2.z, w2.w, w3.x, w3.y, w3.z, w3.w};
  float acc[8];
  {
    const u16x8 v = *(const u16x8*)(h + (size_t)tok * H + c);
#pragma unroll
    for (int i = 0; i < 8; ++i) acc[i] = b2f(v[i]);
  }
#pragma unroll
  for (int wi = 0; wi < 16; ++wi) {
    unsigned bits = wa[wi];
    while (bits) {
      const int bit = __ffs(bits) - 1;
      bits &= bits - 1;
      const int s = wi * 32 + bit;
      const u16x8 u = *(const u16x8*)(h + (size_t)(b * L + s) * H + c);
#pragma unroll
      for (int i = 0; i < 8; ++i) acc[i] += b2f(u[i]);
    }
  }
  u16x8 o;
#pragma unroll
  for (int i = 0; i < 8; ++i) o[i] = f2b(acc[i]);
  *(u16x8*)(T + (size_t)tok * H + c) = o;
}

// zero bm + yv (replaces hipMemsetAsync -> fillBufferAligned, which showed
// ~39us dur at ~0 HBM traffic in r8/r10/r11 traces)
__global__ void k_zero(uint4* __restrict__ p) {
  p[blockIdx.x * 256 + threadIdx.x] = uint4{0, 0, 0, 0};
}

// dedup'd adjacency bitmap
__global__ void k_edges(const int* __restrict__ edges, unsigned* __restrict__ bm) {
  const int t = blockIdx.x * 256 + threadIdx.x;
  const int b = t >> 9, e = t & 511;
  const int u = edges[(size_t)(b * NE + e) * 2 + 0];
  const int v = edges[(size_t)(b * NE + e) * 2 + 1];
  atomicOr(&bm[(size_t)(b * L + u) * 16 + (v >> 5)], 1u << (v & 31));
  atomicOr(&bm[(size_t)(b * L + v) * 16 + (u >> 5)], 1u << (u & 31));
}

// Merged prep: blocks [0,NSEMBT): Semb transpose fp32->bf16 [B*L][KPAD];
//              blocks [NSEMBT,...): weight cvt + rden (needs bm from k_edges).
#define NSEMBT (B * 56)  // 64 * 7 * 8
__global__ __launch_bounds__(256) void k_prep(const float* __restrict__ Semb,
                                              const float* __restrict__ W1,
                                              const float* __restrict__ gW,
                                              const float* __restrict__ lW,
                                              const float* __restrict__ gcnW,
                                              const unsigned* __restrict__ bm,
                                              u16* __restrict__ A0,
                                              u16* __restrict__ W1b, u16* __restrict__ HWGb,
                                              u16* __restrict__ HWLb, u16* __restrict__ GCNb,
                                              float* __restrict__ rden) {
  const int t = threadIdx.x;
  if (blockIdx.x < NSEMBT) {
    const int bid = blockIdx.x;
    const int b = bid / 56, rem = bid - b * 56;
    const int e0 = (rem >> 3) * 64, l0 = (rem & 7) * 64;
    __shared__ u16 tile[64][72];
    {
      const int er = t >> 2, ls = (t & 3) * 16;
      if (e0 + er < EMB) {
        const float* src = Semb + ((size_t)b * EMB + e0 + er) * L + l0 + ls;
#pragma unroll
        for (int i = 0; i < 4; ++i) {
          const float4 v = *(const float4*)(src + i * 4);
          tile[er][ls + i * 4 + 0] = f2b(v.x);
          tile[er][ls + i * 4 + 1] = f2b(v.y);
          tile[er][ls + i * 4 + 2] = f2b(v.z);
          tile[er][ls + i * 4 + 3] = f2b(v.w);
        }
      } else {
#pragma unroll
        for (int i = 0; i < 16; ++i) tile[er][ls + i] = 0;
      }
    }
    __syncthreads();
    {
      const int lr = t >> 2, es = (t & 3) * 16;
      if (e0 + es < KPAD) {  // KPAD=416 not /64: by=6 writes only es<32
        u16x8 v0, v1;
#pragma unroll
        for (int i = 0; i < 8; ++i) v0[i] = tile[es + i][lr];
#pragma unroll
        for (int i = 0; i < 8; ++i) v1[i] = tile[es + 8 + i][lr];
        u16* dst = A0 + (size_t)(b * L + l0 + lr) * KPAD + e0 + es;
        *(u16x8*)dst = v0;
        *(u16x8*)(dst + 8) = v1;
      }
    }
    return;
  }
  int i = (blockIdx.x - NSEMBT) * 256 + t;
  if (i < 256 * KPAD) {
    const int o = i / KPAD, k = i - o * KPAD;
    W1b[i] = (k < EMB) ? f2b(W1[o * EMB + k]) : (u16)0;
    return;
  }
  i -= 256 * KPAD;
  if (i < 2 * H * H) { HWGb[i] = f2b(gW[i]); return; }
  i -= 2 * H * H;
  if (i < 2 * H * H) { HWLb[i] = f2b(lW[i]); return; }
  i -= 2 * H * H;
  if (i < NL * H * H) { GCNb[i] = f2b(gcnW[i]); return; }
  i -= NL * H * H;
  if (i < M_TOT) {
    const uint4* p = (const uint4*)(bm + (size_t)i * 16);
    int c = 0;
#pragma unroll
    for (int w = 0; w < 4; ++w) {
      const uint4 v = p[w];
      c += __popc(v.x) + __popc(v.y) + __popc(v.z) + __popc(v.w);
    }
    rden[i] = 1.f / (1.f + (float)c);
  }
}

// logits + maskA: block B*2 does maskA, blocks 0..B*2-1 do logits
__global__ __launch_bounds__(256) void k_logits(const float* __restrict__ yv,
                                                const float* __restrict__ cb,
                                                const float* __restrict__ lw,
                                                const float* __restrict__ lb,
                                                const int* __restrict__ wids,
                                                const int* __restrict__ y1,
                                                const int* __restrict__ y2,
                                                float* __restrict__ out) {
  if (blockIdx.x == B * 2) {
#pragma unroll
    for (int j = 0; j < 8; ++j) {
      const int idx = j * 256 + threadIdx.x;  // < B*MAXA
      const int b = idx >> 5, q = idx & 31;
      out[B * L + idx] = (y1[b] + q <= y2[b]) ? 1.0f : 0.0f;
    }
    return;
  }
  const int b = blockIdx.x >> 1;
  const int m = ((blockIdx.x & 1) << 8) + threadIdx.x;
  __shared__ float ys[512];
  const float cb0 = cb[0];
  ys[threadIdx.x] = fmaxf(yv[(size_t)b * L + threadIdx.x] + cb0, 0.f);
  ys[threadIdx.x + 256] = fmaxf(yv[(size_t)b * L + 256 + threadIdx.x] + cb0, 0.f);
  __syncthreads();
  float acc = lb[m];
  const float4* wr = (const float4*)(lw + (size_t)m * L);
#pragma unroll 4
  for (int l4 = 0; l4 < 128; ++l4) {
    const float4 w4 = wr[l4];
    acc += ys[l4 * 4] * w4.x + ys[l4 * 4 + 1] * w4.y + ys[l4 * 4 + 2] * w4.z +
           ys[l4 * 4 + 3] * w4.w;
  }
  out[(size_t)b * L + m] = (wids[(size_t)b * L + m] != 0) ? acc : -1.0e30f;
}

extern "C" void kernel_launch(void* const* d_in, const int* in_sizes, int n_in,
                              void* d_out, int out_size, void* d_ws, size_t ws_size,
                              hipStream_t stream) {
  (void)in_sizes; (void)n_in; (void)out_size; (void)ws_size;
  const float* Semb      = (const float*)d_in[0];
  const int*   wids      = (const int*)d_in[1];
  const int*   y1        = (const int*)d_in[2];
  const int*   y2        = (const int*)d_in[3];
  const int*   edges     = (const int*)d_in[4];
  const float* W1        = (const float*)d_in[5];
  const float* hw_lin_W  = (const float*)d_in[6];
  const float* hw_lin_b  = (const float*)d_in[7];
  const float* hw_gate_W = (const float*)d_in[8];
  const float* hw_gate_b = (const float*)d_in[9];
  const float* gcn_W     = (const float*)d_in[10];
  const float* gcn_b     = (const float*)d_in[11];
  const float* conv_W    = (const float*)d_in[12];
  const float* conv_b    = (const float*)d_in[13];
  const float* lin_W     = (const float*)d_in[14];
  const float* lin_b     = (const float*)d_in[15];
  float* out = (float*)d_out;

  char* ws = (char*)d_ws;
  const size_t SZA = (size_t)M_TOT * KPAD * 2;   // 27,262,976
  const size_t SZX = (size_t)M_TOT * H * 2;      // 16,777,216
  u16* A0   = (u16*)(ws);
  u16* P0b  = (u16*)(ws + SZA);
  u16* P1b  = (u16*)(ws + SZA + SZX);
  u16* O0   = (u16*)(ws + SZA + 2 * SZX);
  u16* O1   = (u16*)(ws + SZA + 3 * SZX);
  char* wp  = ws + SZA + 4 * SZX;
  u16* W1b  = (u16*)(wp);                         // 212,992
  u16* HWGb = (u16*)(wp + 212992);                // 262,144
  u16* HWLb = (u16*)(wp + 212992 + 262144);       // 262,144
  u16* GCNb = (u16*)(wp + 212992 + 2 * 262144);   // 393,216
  char* sp  = wp + 212992 + 2 * 262144 + 393216;
  unsigned* bm   = (unsigned*)(sp);               // 2 MB
  float*    yv   = (float*)(sp + 2097152);        // 128 KB (zeroed w/ bm)
  float*    rden = (float*)(sp + 2097152 + 131072);

  // zero bm + yv with our own kernel (2,228,224 B = 544 blocks x 256 x 16B)
  k_zero<<<dim3(544), 256, 0, stream>>>((uint4*)bm);
  k_edges<<<dim3(B * NE / 256), 256, 0, stream>>>(edges, bm);

  // merged prep: Semb transpose + weight cvt + rden
  const int ncvt = 256 * KPAD + 4 * H * H + NL * H * H + M_TOT;
  k_prep<<<dim3(NSEMBT + (ncvt + 255) / 256), 256, 0, stream>>>(
      Semb, W1, hw_gate_W, hw_lin_W, gcn_W, bm, A0, W1b, HWGb, HWLb, GCNb, rden);

  // conv 1x1
  gemm64<0><<<dim3(M_TOT / 64), 256, 0, stream>>>(A0, W1b, nullptr, KPAD, nullptr, nullptr,
                                                  nullptr, nullptr, nullptr, P0b);
  // highway x2 (gate + lin fused; residual re-read from A)
  gemm64<1><<<dim3(M_TOT / 64), 256, 0, stream>>>(P0b, HWGb, HWLb, H, hw_gate_b, hw_lin_b,
                                                  nullptr, nullptr, nullptr, P1b);
  gemm64<1><<<dim3(M_TOT / 64), 256, 0, stream>>>(P1b, HWGb + H * H, HWLb + H * H, H,
                                                  hw_gate_b + H, hw_lin_b + H, nullptr, nullptr,
                                                  nullptr, P0b);
  // GCN layers: high-TLP gather, then GEMM w/ fused yv accumulation
  k_gather<<<dim3(M_TOT / 8), 256, 0, stream>>>(bm, P0b, P1b);
  gemm64<2><<<dim3(M_TOT / 64), 256, 0, stream>>>(P1b, GCNb, nullptr, H, gcn_b, nullptr,
                                                  rden, conv_W, yv, O0);
  k_gather<<<dim3(M_TOT / 8), 256, 0, stream>>>(bm, O0, P0b);
  gemm64<2><<<dim3(M_TOT / 64), 256, 0, stream>>>(P0b, GCNb + H * H, nullptr, H, gcn_b + H,
                                                  nullptr, rden, conv_W + H, yv, O1);
  k_gather<<<dim3(M_TOT / 8), 256, 0, stream>>>(bm, O1, P1b);
  gemm64<3><<<dim3(M_TOT / 64), 256, 0, stream>>>(P1b, GCNb + 2 * H * H, nullptr, H,
                                                  gcn_b + 2 * H, nullptr, rden,
                                                  conv_W + 2 * H, yv, nullptr);

  // head (+ maskA in the extra block)
  k_logits<<<dim3(B * 2 + 1), 256, 0, stream>>>(yv, conv_b, lin_W, lin_b, wids, y1, y2, out);
}

// Round 13
// 174.323 us; speedup vs baseline: 1.3173x; 1.0378x over previous
//
#include <hip/hip_runtime.h>
#include <cstdint>

#define B 64
#define L 512
#define EMB 400
#define KPAD 416
#define H 256
#define NL 3
#define NE 512
#define MAXA 32
#define M_TOT (B * L)

typedef unsigned short u16;
typedef float f32x4 __attribute__((ext_vector_type(4)));
typedef short short8 __attribute__((ext_vector_type(8)));
typedef u16 u16x8 __attribute__((ext_vector_type(8)));

__device__ __forceinline__ float b2f(u16 u) {
  unsigned v = ((unsigned)u) << 16;
  return __builtin_bit_cast(float, v);
}
__device__ __forceinline__ u16 f2b(float f) {
  unsigned u = __builtin_bit_cast(unsigned, f);
  unsigned r = (u + 0x7fffu + ((u >> 16) & 1u)) >> 16;
  return (u16)r;
}

#define GL16(g, l)                                                              \
  __builtin_amdgcn_global_load_lds((const __attribute__((address_space(1))) void*)(g), \
                                   (__attribute__((address_space(3))) void*)(l), 16, 0, 0)

// ---------------------------------------------------------------------------
// FUSED Semb-transpose + conv GEMM. One block = 64 tokens.
// Phase 1: transpose Semb[b][e][l] fp32 -> At (bf16, MFMA chunk layout) via
//          the proven two-stage padded-tile pattern (7 e-tiles: 6x64 + 1x32).
//          tmp tile aliases the Bt region (transpose finishes before staging).
// Phase 2: 13-step k-loop, B single-buffered from L2-hot W1b (512 blocks read
//          the same 213KB weights). LDS total 68KB -> 2 blocks/CU.
// Numerics: same f2b on same values as the split version -> bit-identical.
// ---------------------------------------------------------------------------
__global__ __launch_bounds__(256, 2) void k_convT(const float* __restrict__ Semb,
                                                  const u16* __restrict__ W1b,
                                                  u16* __restrict__ Out) {
  __shared__ u16 smem[64 * KPAD + 256 * 32];   // At (52KB) + Bt (16KB)
  u16* At = smem;
  u16* Bt = smem + 64 * KPAD;
  u16 (*tmp)[72] = (u16(*)[72])Bt;             // 64x72 u16 = 9216B < 16KB

  const int t = threadIdx.x;
  const int wid = t >> 6, lane = t & 63;
  const int m0 = blockIdx.x * 64;
  const int b = m0 >> 9, l0 = m0 & 511;
  const int fr = lane & 15, kg = lane >> 4;
  const int r4 = t >> 2, ksg = t & 3;

  // ---- phase 1: transpose into At ----
  for (int et = 0; et < 7; ++et) {
    const int e0 = et * 64;
    const int erows = (et < 6) ? 64 : 32;      // tile 6 covers e 384..415
    {
      const int er = t >> 2, ls = (t & 3) * 16;
      if (er < erows) {
        if (e0 + er < EMB) {
          const float* src = Semb + ((size_t)b * EMB + e0 + er) * L + l0 + ls;
#pragma unroll
          for (int i = 0; i < 4; ++i) {
            const float4 v = *(const float4*)(src + i * 4);
            tmp[er][ls + i * 4 + 0] = f2b(v.x);
            tmp[er][ls + i * 4 + 1] = f2b(v.y);
            tmp[er][ls + i * 4 + 2] = f2b(v.z);
            tmp[er][ls + i * 4 + 3] = f2b(v.w);
          }
        } else {
#pragma unroll
          for (int i = 0; i < 16; ++i) tmp[er][ls + i] = 0;
        }
      }
    }
    __syncthreads();
    {
      const int lr = t >> 2, es = (t & 3) * 16;
      if (es < erows) {
        u16x8 v0, v1;
#pragma unroll
        for (int i = 0; i < 8; ++i) v0[i] = tmp[es + i][lr];
#pragma unroll
        for (int i = 0; i < 8; ++i) v1[i] = tmp[es + 8 + i][lr];
        const int k = e0 + es;                 // k%16==0
        u16* dst = At + (((size_t)(k >> 5) * 64 + lr) * 4 + ((k & 31) >> 3)) * 8;
        *(u16x8*)dst = v0;
        *(u16x8*)(dst + 8) = v1;
      }
    }
    __syncthreads();
  }

  // ---- phase 2: k-loop (B single-buffered; At resident) ----
  f32x4 acc[4][4] = {};
  for (int kk = 0; kk < (KPAD >> 5); ++kk) {
    const int kc = kk * 32 + ksg * 8;
#pragma unroll
    for (int c = 0; c < 4; ++c)
      GL16(W1b + (size_t)(c * 64 + r4) * KPAD + kc, Bt + (size_t)(c * 256 + wid * 64) * 8);
    asm volatile("s_waitcnt vmcnt(0)" ::: "memory");
    __builtin_amdgcn_s_barrier();
    asm volatile("" ::: "memory");
    short8 af[4], bf[4];
#pragma unroll
    for (int i = 0; i < 4; ++i) {
      af[i] = *(const short8*)(At + ((size_t)(kk * 64 + i * 16 + fr) * 4 + kg) * 8);
      bf[i] = *(const short8*)(Bt + ((size_t)(wid * 64 + i * 16 + fr) * 4 + kg) * 8);
    }
#pragma unroll
    for (int mi = 0; mi < 4; ++mi)
#pragma unroll
      for (int ni = 0; ni < 4; ++ni)
        acc[mi][ni] = __builtin_amdgcn_mfma_f32_16x16x32_bf16(af[mi], bf[ni], acc[mi][ni], 0, 0, 0);
    __builtin_amdgcn_s_barrier();
    asm volatile("" ::: "memory");
  }

  // epilogue: C/D mapping col = lane&15, row = (lane>>4)*4 + reg [m89-verified]
  const int r0 = kg * 4;
  const int c0 = wid * 64 + fr;
#pragma unroll
  for (int ni = 0; ni < 4; ++ni) {
    const int col = c0 + ni * 16;
#pragma unroll
    for (int mi = 0; mi < 4; ++mi)
#pragma unroll
      for (int rr = 0; rr < 4; ++rr)
        Out[(size_t)(m0 + mi * 16 + r0 + rr) * H + col] = f2b(acc[mi][ni][rr]);
  }
}

// ---------------------------------------------------------------------------
// bf16 MFMA GEMM, BM=64 x BN=256, BK=32, counted-vmcnt dbuf (r8-proven).
// EPI 1: highway dual-B (residual re-read from global A);
// EPI 2: gcn relu((acc+2b)*rden), yv += out.cw, store; EPI 3: gcn last (yv only)
// ---------------------------------------------------------------------------
template <int EPI>
__global__ __launch_bounds__(256, 2) void gemm64(
    const u16* __restrict__ A, const u16* __restrict__ Bw, const u16* __restrict__ B2w,
    const int K,
    const float* __restrict__ bias1, const float* __restrict__ bias2,
    const float* __restrict__ rden, const float* __restrict__ cw,
    float* __restrict__ yv, u16* __restrict__ Out) {
  constexpr bool HW = (EPI == 1);
  __shared__ u16 Bl0[256 * 32];
  __shared__ u16 Bl1[256 * 32];
  __shared__ u16 Al0[64 * 32];
  __shared__ u16 Al1[64 * 32];
  __shared__ u16 Cl0[HW ? 256 * 32 : 8];
  __shared__ u16 Cl1[HW ? 256 * 32 : 8];

  const int t = threadIdx.x;
  const int wid = t >> 6, lane = t & 63;
  const int m0 = blockIdx.x * 64;
  const int fr = lane & 15, kg = lane >> 4;
  const int r4 = t >> 2, ksg = t & 3;

  f32x4 acc[4][4] = {};
  f32x4 acc2[4][4] = {};

  auto stage = [&](u16* Ab, u16* Bb, u16* Cb, int kk) {
    const int kc = kk * 32 + ksg * 8;
#pragma unroll
    for (int c = 0; c < 4; ++c)
      GL16(Bw + (size_t)(c * 64 + r4) * K + kc, Bb + (size_t)(c * 256 + wid * 64) * 8);
    if constexpr (HW) {
#pragma unroll
      for (int c = 0; c < 4; ++c)
        GL16(B2w + (size_t)(c * 64 + r4) * K + kc, Cb + (size_t)(c * 256 + wid * 64) * 8);
    }
    GL16(A + (size_t)(m0 + r4) * K + kc, Ab + (size_t)(wid * 64) * 8);
  };
  auto compute = [&](const u16* Ab, const u16* Bb, const u16* Cb) {
    short8 af[4], bf[4], cf[4];
#pragma unroll
    for (int i = 0; i < 4; ++i) {
      af[i] = *(const short8*)(Ab + ((size_t)(i * 16 + fr) * 4 + kg) * 8);
      bf[i] = *(const short8*)(Bb + ((size_t)(wid * 64 + i * 16 + fr) * 4 + kg) * 8);
      if constexpr (HW)
        cf[i] = *(const short8*)(Cb + ((size_t)(wid * 64 + i * 16 + fr) * 4 + kg) * 8);
    }
#pragma unroll
    for (int mi = 0; mi < 4; ++mi)
#pragma unroll
      for (int ni = 0; ni < 4; ++ni) {
        acc[mi][ni] = __builtin_amdgcn_mfma_f32_16x16x32_bf16(af[mi], bf[ni], acc[mi][ni], 0, 0, 0);
        if constexpr (HW)
          acc2[mi][ni] =
              __builtin_amdgcn_mfma_f32_16x16x32_bf16(af[mi], cf[ni], acc2[mi][ni], 0, 0, 0);
      }
  };

  const int nk = K >> 5;
  stage(Al0, Bl0, Cl0, 0);
  for (int kk = 0; kk < nk; ++kk) {
    u16* Ac = (kk & 1) ? Al1 : Al0;
    u16* Bc = (kk & 1) ? Bl1 : Bl0;
    u16* Cc = (kk & 1) ? Cl1 : Cl0;
    u16* An = (kk & 1) ? Al0 : Al1;
    u16* Bn = (kk & 1) ? Bl0 : Bl1;
    u16* Cn = (kk & 1) ? Cl0 : Cl1;
    if (kk + 1 < nk) {
      stage(An, Bn, Cn, kk + 1);
      if constexpr (HW)
        asm volatile("s_waitcnt vmcnt(9)" ::: "memory");
      else
        asm volatile("s_waitcnt vmcnt(5)" ::: "memory");
    } else {
      asm volatile("s_waitcnt vmcnt(0)" ::: "memory");
    }
    __builtin_amdgcn_s_barrier();
    asm volatile("" ::: "memory");
    compute(Ac, Bc, Cc);
    __builtin_amdgcn_s_barrier();
    asm volatile("" ::: "memory");
  }

  const int r0 = kg * 4;
  const int c0 = wid * 64 + fr;
  if constexpr (EPI == 1) {
#pragma unroll
    for (int ni = 0; ni < 4; ++ni) {
      const int col = c0 + ni * 16;
      const float b1 = bias1[col], b2 = bias2[col];
#pragma unroll
      for (int mi = 0; mi < 4; ++mi)
#pragma unroll
        for (int rr = 0; rr < 4; ++rr) {
          const int row = m0 + mi * 16 + r0 + rr;
          const float g = 1.f / (1.f + __expf(-(acc[mi][ni][rr] + b1)));
          const float nn = acc2[mi][ni][rr] + b2;
          const float x = b2f(A[(size_t)row * K + col]);  // residual, L2-hot
          Out[(size_t)row * H + col] = f2b(g * nn + (1.f - g) * x);
        }
    }
  } else {
    float ypart[16];
#pragma unroll
    for (int q = 0; q < 16; ++q) ypart[q] = 0.f;
#pragma unroll
    for (int ni = 0; ni < 4; ++ni) {
      const int col = c0 + ni * 16;
      const float b1 = 2.f * bias1[col];
      const float cwv = cw[col];
#pragma unroll
      for (int mi = 0; mi < 4; ++mi)
#pragma unroll
        for (int rr = 0; rr < 4; ++rr) {
          const int row = m0 + mi * 16 + r0 + rr;
          const float s = (acc[mi][ni][rr] + b1) * rden[row];
          const float rl = s > 0.f ? s : 0.f;
          ypart[mi * 4 + rr] += rl * cwv;
          if constexpr (EPI == 2) Out[(size_t)row * H + col] = f2b(rl);
        }
    }
#pragma unroll
    for (int q = 0; q < 16; ++q) {
      float p = ypart[q];
      p += __shfl_xor(p, 1);
      p += __shfl_xor(p, 2);
      p += __shfl_xor(p, 4);
      p += __shfl_xor(p, 8);
      if (fr == 0) atomicAdd(&yv[m0 + (q >> 2) * 16 + r0 + (q & 3)], p);
    }
  }
}

// T[m,:] = h[m,:] + sum_{s in adj row} h[s,:]  (8 tok/block, u16x8, high TLP)
__global__ __launch_bounds__(256) void k_gather(const unsigned* __restrict__ bm,
                                                const u16* __restrict__ h,
                                                u16* __restrict__ T) {
  const int t = threadIdx.x;
  const int tok = blockIdx.x * 8 + (t >> 5);
  const int b = tok >> 9;
  const int c = (t & 31) * 8;
  const uint4* wp4 = (const uint4*)(bm + (size_t)tok * 16);
  const uint4 w0 = wp4[0], w1 = wp4[1], w2 = wp4[2], w3 = wp4[3];
  const unsigned wa[16] = {w0.x, w0.y, w0.z, w0.w, w1.x, w1.y, w1.z, w1.w,
                           w2.x, w2.y, w2.z, w2.w, w3.x, w3.y, w3.z, w3.w};
  float acc[8];
  {
    const u16x8 v = *(const u16x8*)(h + (size_t)tok * H + c);
#pragma unroll
    for (int i = 0; i < 8; ++i) acc[i] = b2f(v[i]);
  }
#pragma unroll
  for (int wi = 0; wi < 16; ++wi) {
    unsigned bits = wa[wi];
    while (bits) {
      const int bit = __ffs(bits) - 1;
      bits &= bits - 1;
      const int s = wi * 32 + bit;
      const u16x8 u = *(const u16x8*)(h + (size_t)(b * L + s) * H + c);
#pragma unroll
      for (int i = 0; i < 8; ++i) acc[i] += b2f(u[i]);
    }
  }
  u16x8 o;
#pragma unroll
  for (int i = 0; i < 8; ++i) o[i] = f2b(acc[i]);
  *(u16x8*)(T + (size_t)tok * H + c) = o;
}

// zero bm + yv
__global__ void k_zero(uint4* __restrict__ p) {
  p[blockIdx.x * 256 + threadIdx.x] = uint4{0, 0, 0, 0};
}

// dedup'd adjacency bitmap
__global__ void k_edges(const int* __restrict__ edges, unsigned* __restrict__ bm) {
  const int t = blockIdx.x * 256 + threadIdx.x;
  const int b = t >> 9, e = t & 511;
  const int u = edges[(size_t)(b * NE + e) * 2 + 0];
  const int v = edges[(size_t)(b * NE + e) * 2 + 1];
  atomicOr(&bm[(size_t)(b * L + u) * 16 + (v >> 5)], 1u << (v & 31));
  atomicOr(&bm[(size_t)(b * L + v) * 16 + (u >> 5)], 1u << (u & 31));
}

// prep: weight cvt + rden (sembT moved into k_convT)
__global__ void k_prep(const float* __restrict__ W1, const float* __restrict__ gW,
                       const float* __restrict__ lW, const float* __restrict__ gcnW,
                       const unsigned* __restrict__ bm,
                       u16* __restrict__ W1b, u16* __restrict__ HWGb,
                       u16* __restrict__ HWLb, u16* __restrict__ GCNb,
                       float* __restrict__ rden) {
  int i = blockIdx.x * 256 + threadIdx.x;
  if (i < 256 * KPAD) {
    const int o = i / KPAD, k = i - o * KPAD;
    W1b[i] = (k < EMB) ? f2b(W1[o * EMB + k]) : (u16)0;
    return;
  }
  i -= 256 * KPAD;
  if (i < 2 * H * H) { HWGb[i] = f2b(gW[i]); return; }
  i -= 2 * H * H;
  if (i < 2 * H * H) { HWLb[i] = f2b(lW[i]); return; }
  i -= 2 * H * H;
  if (i < NL * H * H) { GCNb[i] = f2b(gcnW[i]); return; }
  i -= NL * H * H;
  if (i < M_TOT) {
    const uint4* p = (const uint4*)(bm + (size_t)i * 16);
    int c = 0;
#pragma unroll
    for (int w = 0; w < 4; ++w) {
      const uint4 v = p[w];
      c += __popc(v.x) + __popc(v.y) + __popc(v.z) + __popc(v.w);
    }
    rden[i] = 1.f / (1.f + (float)c);
  }
}

// logits + maskA
__global__ __launch_bounds__(256) void k_logits(const float* __restrict__ yv,
                                                const float* __restrict__ cb,
                                                const float* __restrict__ lw,
                                                const float* __restrict__ lb,
                                                const int* __restrict__ wids,
                                                const int* __restrict__ y1,
                                                const int* __restrict__ y2,
                                                float* __restrict__ out) {
  if (blockIdx.x == B * 2) {
#pragma unroll
    for (int j = 0; j < 8; ++j) {
      const int idx = j * 256 + threadIdx.x;
      const int b = idx >> 5, q = idx & 31;
      out[B * L + idx] = (y1[b] + q <= y2[b]) ? 1.0f : 0.0f;
    }
    return;
  }
  const int b = blockIdx.x >> 1;
  const int m = ((blockIdx.x & 1) << 8) + threadIdx.x;
  __shared__ float ys[512];
  const float cb0 = cb[0];
  ys[threadIdx.x] = fmaxf(yv[(size_t)b * L + threadIdx.x] + cb0, 0.f);
  ys[threadIdx.x + 256] = fmaxf(yv[(size_t)b * L + 256 + threadIdx.x] + cb0, 0.f);
  __syncthreads();
  float acc = lb[m];
  const float4* wr = (const float4*)(lw + (size_t)m * L);
#pragma unroll 4
  for (int l4 = 0; l4 < 128; ++l4) {
    const float4 w4 = wr[l4];
    acc += ys[l4 * 4] * w4.x + ys[l4 * 4 + 1] * w4.y + ys[l4 * 4 + 2] * w4.z +
           ys[l4 * 4 + 3] * w4.w;
  }
  out[(size_t)b * L + m] = (wids[(size_t)b * L + m] != 0) ? acc : -1.0e30f;
}

extern "C" void kernel_launch(void* const* d_in, const int* in_sizes, int n_in,
                              void* d_out, int out_size, void* d_ws, size_t ws_size,
                              hipStream_t stream) {
  (void)in_sizes; (void)n_in; (void)out_size; (void)ws_size;
  const float* Semb      = (const float*)d_in[0];
  const int*   wids      = (const int*)d_in[1];
  const int*   y1        = (const int*)d_in[2];
  const int*   y2        = (const int*)d_in[3];
  const int*   edges     = (const int*)d_in[4];
  const float* W1        = (const float*)d_in[5];
  const float* hw_lin_W  = (const float*)d_in[6];
  const float* hw_lin_b  = (const float*)d_in[7];
  const float* hw_gate_W = (const float*)d_in[8];
  const float* hw_gate_b = (const float*)d_in[9];
  const float* gcn_W     = (const float*)d_in[10];
  const float* gcn_b     = (const float*)d_in[11];
  const float* conv_W    = (const float*)d_in[12];
  const float* conv_b    = (const float*)d_in[13];
  const float* lin_W     = (const float*)d_in[14];
  const float* lin_b     = (const float*)d_in[15];
  float* out = (float*)d_out;

  char* ws = (char*)d_ws;
  const size_t SZX = (size_t)M_TOT * H * 2;      // 16,777,216
  u16* P0b  = (u16*)(ws);
  u16* P1b  = (u16*)(ws + SZX);
  u16* O0   = (u16*)(ws + 2 * SZX);
  u16* O1   = (u16*)(ws + 3 * SZX);
  char* wp  = ws + 4 * SZX;
  u16* W1b  = (u16*)(wp);                         // 256*416*2 = 212,992
  u16* HWGb = (u16*)(wp + 212992);                // 262,144
  u16* HWLb = (u16*)(wp + 212992 + 262144);       // 262,144
  u16* GCNb = (u16*)(wp + 212992 + 2 * 262144);   // 393,216
  char* sp  = wp + 212992 + 2 * 262144 + 393216;
  unsigned* bm   = (unsigned*)(sp);               // 2 MB
  float*    yv   = (float*)(sp + 2097152);        // 128 KB (zeroed w/ bm)
  float*    rden = (float*)(sp + 2097152 + 131072);

  // zero bm + yv (2,228,224 B = 544 blocks x 256 x 16B)
  k_zero<<<dim3(544), 256, 0, stream>>>((uint4*)bm);
  k_edges<<<dim3(B * NE / 256), 256, 0, stream>>>(edges, bm);

  // prep: weight conversions + rden
  const int ncvt = 256 * KPAD + 4 * H * H + NL * H * H + M_TOT;
  k_prep<<<dim3((ncvt + 255) / 256), 256, 0, stream>>>(W1, hw_gate_W, hw_lin_W, gcn_W, bm,
                                                       W1b, HWGb, HWLb, GCNb, rden);

  // fused transpose + conv 1x1
  k_convT<<<dim3(M_TOT / 64), 256, 0, stream>>>(Semb, W1b, P0b);

  // highway x2 (gate + lin fused; residual re-read from A)
  gemm64<1><<<dim3(M_TOT / 64), 256, 0, stream>>>(P0b, HWGb, HWLb, H, hw_gate_b, hw_lin_b,
                                                  nullptr, nullptr, nullptr, P1b);
  gemm64<1><<<dim3(M_TOT / 64), 256, 0, stream>>>(P1b, HWGb + H * H, HWLb + H * H, H,
                                                  hw_gate_b + H, hw_lin_b + H, nullptr, nullptr,
                                                  nullptr, P0b);
  // GCN layers: high-TLP gather, then GEMM w/ fused yv accumulation
  k_gather<<<dim3(M_TOT / 8), 256, 0, stream>>>(bm, P0b, P1b);
  gemm64<2><<<dim3(M_TOT / 64), 256, 0, stream>>>(P1b, GCNb, nullptr, H, gcn_b, nullptr,
                                                  rden, conv_W, yv, O0);
  k_gather<<<dim3(M_TOT / 8), 256, 0, stream>>>(bm, O0, P0b);
  gemm64<2><<<dim3(M_TOT / 64), 256, 0, stream>>>(P0b, GCNb + H * H, nullptr, H, gcn_b + H,
                                                  nullptr, rden, conv_W + H, yv, O1);
  k_gather<<<dim3(M_TOT / 8), 256, 0, stream>>>(bm, O1, P1b);
  gemm64<3><<<dim3(M_TOT / 64), 256, 0, stream>>>(P1b, GCNb + 2 * H * H, nullptr, H,
                                                  gcn_b + 2 * H, nullptr, rden,
                                                  conv_W + 2 * H, yv, nullptr);

  // head (+ maskA in the extra block)
  k_logits<<<dim3(B * 2 + 1), 256, 0, stream>>>(yv, conv_b, lin_W, lin_b, wids, y1, y2, out);
}